// Round 8
// baseline (70.168 us; speedup 1.0000x reference)
//
#include <hip/hip_runtime.h>

typedef float f4 __attribute__((ext_vector_type(4)));
typedef short s8v __attribute__((ext_vector_type(8)));        // 8 bf16
typedef unsigned int u2v __attribute__((ext_vector_type(2)));
typedef unsigned int u4v __attribute__((ext_vector_type(4)));

#define B_ 32
#define T_ 1024
#define J_ 128
#define D_ 256

__device__ inline unsigned short f2bf(float x) {
    unsigned int u = __float_as_uint(x);
    u += 0x7fffu + ((u >> 16) & 1u);      // RNE
    return (unsigned short)(u >> 16);
}

__device__ __forceinline__ void ldsload16(const void* g, void* l) {
    __builtin_amdgcn_global_load_lds(
        (const __attribute__((address_space(1))) void*)g,
        (__attribute__((address_space(3))) void*)l, 16, 0, 0);
}

// ---------------- K_pre: fused Bqh = bf16(w3*q+w1), sq = q.w2, qTh = bf16 transpose ----------------
__global__ __launch_bounds__(256) void k_pre(const float* __restrict__ q, const float* __restrict__ w,
                                             unsigned short* __restrict__ Bqh, float* __restrict__ sq,
                                             unsigned short* __restrict__ qTh) {
    __shared__ float t_[16][260];
    int b = blockIdx.x >> 3, jt = blockIdx.x & 7;
    int tid = threadIdx.x;
    const float* qb = q + (b * J_ + jt * 16) * D_;

#pragma unroll
    for (int k = 0; k < 4; k++) {
        int idx = tid + (k << 8);              // f4 id over 16x64
        int jj = idx >> 6, d4 = idx & 63;
        f4 v = *(const f4*)(qb + jj * D_ + (d4 << 2));
        *(f4*)&t_[jj][d4 << 2] = v;
        f4 w1v = *(const f4*)(w + (d4 << 2));
        f4 w3v = *(const f4*)(w + 2 * D_ + (d4 << 2));
        u2v p;
        p[0] = (unsigned int)f2bf(w3v[0] * v[0] + w1v[0]) | ((unsigned int)f2bf(w3v[1] * v[1] + w1v[1]) << 16);
        p[1] = (unsigned int)f2bf(w3v[2] * v[2] + w1v[2]) | ((unsigned int)f2bf(w3v[3] * v[3] + w1v[3]) << 16);
        *(u2v*)(Bqh + (b * J_ + jt * 16 + jj) * D_ + (d4 << 2)) = p;
    }
    __syncthreads();

    // sq: 16 threads per j row
    {
        int jj = tid >> 4, dg = tid & 15;
        float p = 0.f;
#pragma unroll
        for (int i = 0; i < 16; i++) {
            int d = (dg << 4) + i;
            p += t_[jj][d] * w[D_ + d];
        }
#pragma unroll
        for (int m = 8; m >= 1; m >>= 1) p += __shfl_xor(p, m);
        if (dg == 0) sq[b * J_ + jt * 16 + jj] = p;
    }

    // qT: thread = d; write 16 j's (32 B) as two u4v
    {
        int dd = tid;
        unsigned int pk[8];
#pragma unroll
        for (int i = 0; i < 8; i++) {
            pk[i] = (unsigned int)f2bf(t_[2 * i][dd]) | ((unsigned int)f2bf(t_[2 * i + 1][dd]) << 16);
        }
        u4v v0, v1;
        v0[0] = pk[0]; v0[1] = pk[1]; v0[2] = pk[2]; v0[3] = pk[3];
        v1[0] = pk[4]; v1[1] = pk[5]; v1[2] = pk[6]; v1[3] = pk[7];
        unsigned short* dst = qTh + (b * D_ + dd) * J_ + jt * 16;
        *(u4v*)dst = v0;
        *(u4v*)(dst + 8) = v1;
    }
}

// ---------------- K2: gl_lds-staged MFMA S -> merged softmax -> MFMA PV -> q1,q2,q3 + q2c partials ----------------
__global__ __launch_bounds__(256, 3) void k_main(const float* __restrict__ ctx,
                                                 const unsigned short* __restrict__ Bqh,
                                                 const unsigned short* __restrict__ qTh,
                                                 const float* __restrict__ sq,
                                                 float* __restrict__ pq2c, float* __restrict__ pms,
                                                 float* __restrict__ out) {
    __shared__ __align__(16) char lds[41600];
    char* B0 = lds;                     // 16 KB
    char* B1 = lds + 16384;             // 16 KB
    char* Ps = lds + 32768;             // 8 KB: P 32x128 bf16, swizzled
    float* sc = (float*)(lds + 40960);  // 512 B softmax scratch
    float* mrow = (float*)(lds + 41472);// 128 B row maxes

    int b  = blockIdx.x >> 5;
    int t0 = (blockIdx.x & 31) << 5;
    int tid = threadIdx.x;
    int w = tid >> 6, l = tid & 63, lr = l & 15, lq = l >> 4;
    int rg = w & 1, ch = w >> 1;          // phase A: row-group / j-half
    int R0 = rg << 4;

    const unsigned short* BqB  = Bqh + b * J_ * D_;
    const unsigned short* qThB = qTh + b * D_ * J_;

    auto stageBq = [&](char* buf, int qt) {
#pragma unroll
        for (int i = 0; i < 4; i++) {
            int g = tid + (i << 8);
            int jr = g >> 3, c = g & 7;
            ldsload16(BqB + jr * D_ + (qt << 6) + ((c ^ (jr & 7)) << 3),
                      buf + (i << 12) + (w << 10));
        }
    };
    auto stageQ = [&](char* buf, int st) {
#pragma unroll
        for (int i = 0; i < 4; i++) {
            int g = tid + (i << 8);
            int dr = g >> 4, c = g & 15;
            ldsload16(qThB + ((st << 6) + dr) * J_ + ((c ^ (dr & 7)) << 3),
                      buf + (i << 12) + (w << 10));
        }
    };

    f4 acc[4];
#pragma unroll
    for (int nf = 0; nf < 4; nf++) acc[nf] = (f4){0.f, 0.f, 0.f, 0.f};

    stageBq(B0, 0);
    stageBq(B1, 1);

    // ctx rows -> bf16 A-frags
    const float* ctxA = ctx + (b * T_ + t0 + R0 + lr) * D_;
    s8v af[8];
    {
        f4 c0[8], c1[8];
#pragma unroll
        for (int k = 0; k < 8; k++) {
            c0[k] = *(const f4*)(ctxA + k * 32 + lq * 8);
            c1[k] = *(const f4*)(ctxA + k * 32 + lq * 8 + 4);
        }
#pragma unroll
        for (int k = 0; k < 8; k++) {
            union { unsigned short u[8]; s8v v; } t;
#pragma unroll
            for (int e = 0; e < 4; e++) { t.u[e] = f2bf(c0[k][e]); t.u[e + 4] = f2bf(c1[k][e]); }
            af[k] = t.v;
        }
    }

    auto mfmaA = [&](char* buf, int qt) {
#pragma unroll
        for (int kk = 0; kk < 2; kk++)
#pragma unroll
            for (int nf = 0; nf < 4; nf++) {
                int jr = (ch << 6) + (nf << 4) + lr;
                s8v bv = *(const s8v*)(buf + (jr << 7) + ((((kk << 2) | lq) ^ (jr & 7)) << 4));
                acc[nf] = __builtin_amdgcn_mfma_f32_16x16x32_bf16(af[(qt << 1) | kk], bv, acc[nf], 0, 0, 0);
            }
    };

    __syncthreads();               // S1: q0,q1 staged
    mfmaA(B0, 0);
    __syncthreads();               // S2: B0 free
    stageBq(B0, 2);
    mfmaA(B1, 1);
    __syncthreads();               // S3: q2 staged, B1 free
    stageBq(B1, 3);
    mfmaA(B0, 2);
    __syncthreads();               // S4: q3 staged, B0 free
    stageQ(B0, 0);                 // P-stage0 flies under q3 MFMAs
    mfmaA(B1, 3);

    // ---- softmax partials over this wave's 64 cols ----
    float sqv[4];
#pragma unroll
    for (int nf = 0; nf < 4; nf++) sqv[nf] = sq[b * J_ + (ch << 6) + (nf << 4) + lr];
    float mp[4];
#pragma unroll
    for (int r = 0; r < 4; r++) {
        float m = -1e30f;
#pragma unroll
        for (int nf = 0; nf < 4; nf++) { acc[nf][r] += sqv[nf]; m = fmaxf(m, acc[nf][r]); }
#pragma unroll
        for (int msk = 8; msk >= 1; msk >>= 1) m = fmaxf(m, __shfl_xor(m, msk));
        float s = 0.f;
#pragma unroll
        for (int nf = 0; nf < 4; nf++) { float e = __expf(acc[nf][r] - m); acc[nf][r] = e; s += e; }
#pragma unroll
        for (int msk = 8; msk >= 1; msk >>= 1) s += __shfl_xor(s, msk);
        mp[r] = m;
        if (lr == 0) {
            int row = R0 + (lq << 2) + r;
            sc[(row << 2) + (ch << 1)] = m;
            sc[(row << 2) + (ch << 1) + 1] = s;
        }
    }
    __syncthreads();               // S5: sc visible, B1 free, stage0 staged
    stageQ(B1, 1);                 // stage1 flies under merge

    // ---- merge halves, write P (bf16 swizzled) and mrow ----
#pragma unroll
    for (int r = 0; r < 4; r++) {
        int row = R0 + (lq << 2) + r;
        float m0 = sc[(row << 2)],     s0 = sc[(row << 2) + 1];
        float m1 = sc[(row << 2) + 2], s1 = sc[(row << 2) + 3];
        float m = fmaxf(m0, m1);
        float sum = s0 * __expf(m0 - m) + s1 * __expf(m1 - m);
        float scale = __expf(mp[r] - m) / sum;
#pragma unroll
        for (int nf = 0; nf < 4; nf++) {
            int cc = (ch << 6) + (nf << 4) + lr;
            int chunk = cc >> 3;
            *(unsigned short*)(Ps + row * 256 + ((chunk ^ (row & 7)) << 4) + ((lr & 7) << 1)) =
                f2bf(acc[nf][r] * scale);
        }
        if (ch == 0 && lr == 0) mrow[row] = m;
    }
    __syncthreads();               // S6: Ps + mrow visible, stage1 staged

    // ---- phase B: P(32x128) . qT(256x128)^T, 4 stages ----
    int dh2 = w >> 1;
    int prow = R0 + lr;
    s8v pf[4];
#pragma unroll
    for (int jk = 0; jk < 4; jk++)
        pf[jk] = *(const s8v*)(Ps + prow * 256 + ((((jk << 2) + lq) ^ (prow & 7)) << 4));

    f4 acc2[8];
#pragma unroll
    for (int ai = 0; ai < 8; ai++) acc2[ai] = (f4){0.f, 0.f, 0.f, 0.f};

    auto mfmaB = [&](char* rb, int s) {
#pragma unroll
        for (int df2 = 0; df2 < 2; df2++) {
            int dr = (dh2 << 5) + (df2 << 4) + lr;
            int ai = (s << 1) + df2;
#pragma unroll
            for (int jk = 0; jk < 4; jk++) {
                s8v bv = *(const s8v*)(rb + (dr << 8) + ((((jk << 2) + lq) ^ (dr & 7)) << 4));
                acc2[ai] = __builtin_amdgcn_mfma_f32_16x16x32_bf16(pf[jk], bv, acc2[ai], 0, 0, 0);
            }
        }
    };

    mfmaB(B0, 0);
    __syncthreads();               // S7: B0 free
    stageQ(B0, 2);
    mfmaB(B1, 1);
    __syncthreads();               // S8: B1 free, stage2 staged
    stageQ(B1, 3);
    mfmaB(B0, 2);
    __syncthreads();               // S9: stage3 staged
    mfmaB(B1, 3);
    __syncthreads();               // S10: bufs free for epilogue

    // ---- epilogue: acc2 -> LDS (swizzled) -> f4-coalesced nt-stores of q1,q2,q3 ----
    float* cq = (float*)lds;       // 32 rows x 256 cols fp32 = 32 KB
#pragma unroll
    for (int s2 = 0; s2 < 4; s2++)
#pragma unroll
        for (int df2 = 0; df2 < 2; df2++) {
            int col = (s2 << 6) + (dh2 << 5) + (df2 << 4) + lr;
            int ai = (s2 << 1) + df2;
            int chunk = col >> 2;
#pragma unroll
            for (int r = 0; r < 4; r++) {
                int row = R0 + (lq << 2) + r;
                *(float*)((char*)cq + (row << 10) + ((chunk ^ (row & 7)) << 4) + ((col & 3) << 2)) = acc2[ai][r];
            }
        }
    __syncthreads();

    {
        int row = tid >> 3;                   // 0..31
        int o = b * T_ + t0 + row;
        const float* crow = ctx + o * D_;
        float* orow = out + o * 1024;
#pragma unroll
        for (int i = 0; i < 8; i++) {
            int col4 = (i << 5) + ((tid & 7) << 2);
            int chunk = col4 >> 2;
            f4 val = *(const f4*)((char*)cq + (row << 10) + ((chunk ^ (row & 7)) << 4));
            f4 cx = *(const f4*)(crow + col4);
            f4 v3 = cx * val;
            __builtin_nontemporal_store(cx, (f4*)(orow + col4));
            __builtin_nontemporal_store(val, (f4*)(orow + 256 + col4));
            __builtin_nontemporal_store(v3, (f4*)(orow + 512 + col4));
        }
    }

    // ---- block-local q2c partial: p[d] = sum_t exp(mrow[t]-mblk)*ctx[t,d] (ctx rows L2-hot) ----
    {
        float mblk = -1e30f;
#pragma unroll 8
        for (int t = 0; t < 32; t++) mblk = fmaxf(mblk, mrow[t]);
        float sblk = 0.f, q2a = 0.f;
        const float* cpart = ctx + (b * T_ + t0) * D_ + tid;
#pragma unroll 4
        for (int t = 0; t < 32; t++) {
            float e = __expf(mrow[t] - mblk);
            sblk += e;
            q2a += e * cpart[t * D_];
        }
        pq2c[blockIdx.x * 256 + tid] = q2a;
        if (tid == 0) { pms[blockIdx.x * 2] = mblk; pms[blockIdx.x * 2 + 1] = sblk; }
    }
}

// ---------------- K_tail: merge partials -> q2c; write quarter 4 ----------------
__global__ __launch_bounds__(256) void k_tail(const float* __restrict__ ctx,
                                              const float* __restrict__ pq2c, const float* __restrict__ pms,
                                              float* __restrict__ out) {
    int b = blockIdx.x >> 5, tc = blockIdx.x & 31;
    int tid = threadIdx.x;
    const float* pm = pms + b * 64;

    float mx = -1e30f;
#pragma unroll 8
    for (int i = 0; i < 32; i++) mx = fmaxf(mx, pm[2 * i]);
    float sm = 0.f, q2 = 0.f;
#pragma unroll 4
    for (int i = 0; i < 32; i++) {
        float e = __expf(pm[2 * i] - mx);
        sm += pm[2 * i + 1] * e;
        q2 += e * pq2c[((b << 5) + i) * 256 + tid];
    }
    q2 /= sm;
    __shared__ float q2s[256];
    q2s[tid] = q2;
    __syncthreads();

    int row = tid >> 3;
    int o = b * T_ + tc * 32 + row;
    const float* crow = ctx + o * D_;
    float* orow = out + o * 1024;
#pragma unroll
    for (int i = 0; i < 8; i++) {
        int col4 = (i << 5) + ((tid & 7) << 2);
        f4 cx = *(const f4*)(crow + col4);
        f4 qv = *(const f4*)&q2s[col4];
        f4 r = cx * qv;
        __builtin_nontemporal_store(r, (f4*)(orow + 768 + col4));
    }
}

extern "C" void kernel_launch(void* const* d_in, const int* in_sizes, int n_in,
                              void* d_out, int out_size, void* d_ws, size_t ws_size,
                              hipStream_t stream) {
    const float* ctx   = (const float*)d_in[0];
    const float* query = (const float*)d_in[1];
    const float* w     = (const float*)d_in[2];
    float* out = (float*)d_out;

    unsigned short* Bqh = (unsigned short*)d_ws;        // 2 MB
    unsigned short* qTh = Bqh + B_ * J_ * D_;           // 2 MB
    float* fws = (float*)(qTh + B_ * J_ * D_);
    float* sq   = fws;                                  // 4096 floats
    float* pq2c = fws + 4096;                           // 1024*256 floats (1 MB)
    float* pms  = fws + 4096 + 1024 * 256;              // 2048 floats

    k_pre<<<B_ * 8, 256, 0, stream>>>(query, w, Bqh, sq, qTh);
    k_main<<<B_ * (T_ / 32), 256, 0, stream>>>(ctx, Bqh, qTh, sq, pq2c, pms, out);
    k_tail<<<B_ * 32, 256, 0, stream>>>(ctx, pq2c, pms, out);
}

// Round 9
// 66.738 us; speedup vs baseline: 1.0514x; 1.0514x over previous
//
#include <hip/hip_runtime.h>

typedef float f4 __attribute__((ext_vector_type(4)));
typedef float f2 __attribute__((ext_vector_type(2)));
typedef short s8v __attribute__((ext_vector_type(8)));        // 8 bf16
typedef unsigned int u2v __attribute__((ext_vector_type(2)));
typedef unsigned int u4v __attribute__((ext_vector_type(4)));

#define B_ 32
#define T_ 1024
#define J_ 128
#define D_ 256

__device__ inline unsigned short f2bf(float x) {
    unsigned int u = __float_as_uint(x);
    u += 0x7fffu + ((u >> 16) & 1u);      // RNE
    return (unsigned short)(u >> 16);
}

__device__ __forceinline__ void ldsload16(const void* g, void* l) {
    __builtin_amdgcn_global_load_lds(
        (const __attribute__((address_space(1))) void*)g,
        (__attribute__((address_space(3))) void*)l, 16, 0, 0);
}

// ---------------- K_pre: fused Bqh = bf16(w3*q+w1), sq = q.w2, qTh = bf16 transpose ----------------
__global__ __launch_bounds__(256) void k_pre(const float* __restrict__ q, const float* __restrict__ w,
                                             unsigned short* __restrict__ Bqh, float* __restrict__ sq,
                                             unsigned short* __restrict__ qTh) {
    __shared__ float t_[16][260];
    int b = blockIdx.x >> 3, jt = blockIdx.x & 7;
    int tid = threadIdx.x;
    const float* qb = q + (b * J_ + jt * 16) * D_;

#pragma unroll
    for (int k = 0; k < 4; k++) {
        int idx = tid + (k << 8);              // f4 id over 16x64
        int jj = idx >> 6, d4 = idx & 63;
        f4 v = *(const f4*)(qb + jj * D_ + (d4 << 2));
        *(f4*)&t_[jj][d4 << 2] = v;
        f4 w1v = *(const f4*)(w + (d4 << 2));
        f4 w3v = *(const f4*)(w + 2 * D_ + (d4 << 2));
        u2v p;
        p[0] = (unsigned int)f2bf(w3v[0] * v[0] + w1v[0]) | ((unsigned int)f2bf(w3v[1] * v[1] + w1v[1]) << 16);
        p[1] = (unsigned int)f2bf(w3v[2] * v[2] + w1v[2]) | ((unsigned int)f2bf(w3v[3] * v[3] + w1v[3]) << 16);
        *(u2v*)(Bqh + (b * J_ + jt * 16 + jj) * D_ + (d4 << 2)) = p;
    }
    __syncthreads();

    // sq: 16 threads per j row
    {
        int jj = tid >> 4, dg = tid & 15;
        float p = 0.f;
#pragma unroll
        for (int i = 0; i < 16; i++) {
            int d = (dg << 4) + i;
            p += t_[jj][d] * w[D_ + d];
        }
#pragma unroll
        for (int m = 8; m >= 1; m >>= 1) p += __shfl_xor(p, m);
        if (dg == 0) sq[b * J_ + jt * 16 + jj] = p;
    }

    // qT: thread = d; write 16 j's (32 B) as two u4v
    {
        int dd = tid;
        unsigned int pk[8];
#pragma unroll
        for (int i = 0; i < 8; i++) {
            pk[i] = (unsigned int)f2bf(t_[2 * i][dd]) | ((unsigned int)f2bf(t_[2 * i + 1][dd]) << 16);
        }
        u4v v0, v1;
        v0[0] = pk[0]; v0[1] = pk[1]; v0[2] = pk[2]; v0[3] = pk[3];
        v1[0] = pk[4]; v1[1] = pk[5]; v1[2] = pk[6]; v1[3] = pk[7];
        unsigned short* dst = qTh + (b * D_ + dd) * J_ + jt * 16;
        *(u4v*)dst = v0;
        *(u4v*)(dst + 8) = v1;
    }
}

// ---------------- K2: 4-blocks/CU MFMA S -> merged softmax -> MFMA PV -> q1,q2,q3 + q2c partials ----------------
__global__ __launch_bounds__(256, 4) void k_main(const float* __restrict__ ctx,
                                                 const unsigned short* __restrict__ Bqh,
                                                 const unsigned short* __restrict__ qTh,
                                                 const float* __restrict__ sq,
                                                 float* __restrict__ pq2c, float* __restrict__ pms,
                                                 float* __restrict__ out) {
    __shared__ __align__(16) char lds[40960];
    char* B0 = lds;                     // 16 KB
    char* B1 = lds + 16384;             // 16 KB
    char* Ps = lds + 32768;             // 8 KB: P 32x128 bf16, swizzled
    float* sc = (float*)B1;             // 512 B overlay: live only between S5 and S6

    int bid = blockIdx.x;
    int b  = ((bid & 7) << 2) | ((bid >> 3) & 3);   // XCD-clustered: all 32 blocks of b share bid%8
    int tc = bid >> 5;
    int t0 = tc << 5;
    int tid = threadIdx.x;
    int w = tid >> 6, l = tid & 63, lr = l & 15, lq = l >> 4;
    int rg = w & 1, ch = w >> 1;          // row-group / j-half (phase A), d-half (phase B, partial)
    int R0 = rg << 4;

    const unsigned short* BqB  = Bqh + b * J_ * D_;
    const unsigned short* qThB = qTh + b * D_ * J_;

    auto stageBq = [&](char* buf, int qt) {
#pragma unroll
        for (int i = 0; i < 4; i++) {
            int g = tid + (i << 8);
            int jr = g >> 3, c = g & 7;
            ldsload16(BqB + jr * D_ + (qt << 6) + ((c ^ (jr & 7)) << 3),
                      buf + (i << 12) + (w << 10));
        }
    };
    auto stageQ = [&](char* buf, int st) {
#pragma unroll
        for (int i = 0; i < 4; i++) {
            int g = tid + (i << 8);
            int dr = g >> 4, c = g & 15;
            ldsload16(qThB + ((st << 6) + dr) * J_ + ((c ^ (dr & 7)) << 3),
                      buf + (i << 12) + (w << 10));
        }
    };

    f4 acc[4];
#pragma unroll
    for (int nf = 0; nf < 4; nf++) acc[nf] = (f4){0.f, 0.f, 0.f, 0.f};

    stageBq(B0, 0);
    stageBq(B1, 1);

    // ctx rows -> bf16 A-frags (convert per-k to limit register spike)
    const float* ctxA = ctx + (b * T_ + t0 + R0 + lr) * D_;
    s8v af[8];
#pragma unroll
    for (int k = 0; k < 8; k++) {
        f4 a0 = *(const f4*)(ctxA + k * 32 + lq * 8);
        f4 a1 = *(const f4*)(ctxA + k * 32 + lq * 8 + 4);
        union { unsigned short u[8]; s8v v; } t;
#pragma unroll
        for (int e = 0; e < 4; e++) { t.u[e] = f2bf(a0[e]); t.u[e + 4] = f2bf(a1[e]); }
        af[k] = t.v;
    }

    auto mfmaA = [&](char* buf, int qt) {
#pragma unroll
        for (int kk = 0; kk < 2; kk++)
#pragma unroll
            for (int nf = 0; nf < 4; nf++) {
                int jr = (ch << 6) + (nf << 4) + lr;
                s8v bv = *(const s8v*)(buf + (jr << 7) + ((((kk << 2) | lq) ^ (jr & 7)) << 4));
                acc[nf] = __builtin_amdgcn_mfma_f32_16x16x32_bf16(af[(qt << 1) | kk], bv, acc[nf], 0, 0, 0);
            }
    };

    __syncthreads();               // S1: q0,q1 staged
    mfmaA(B0, 0);
    __syncthreads();               // S2: B0 free
    stageBq(B0, 2);
    mfmaA(B1, 1);
    __syncthreads();               // S3: q2 staged, B1 free
    stageBq(B1, 3);
    mfmaA(B0, 2);
    __syncthreads();               // S4: q3 staged, B0 free
    stageQ(B0, 0);                 // P-stage0 flies under q3 MFMAs
    mfmaA(B1, 3);

    // ---- softmax partials over this wave's 64 cols (keep in regs until B1 is free) ----
    float sqv[4];
#pragma unroll
    for (int nf = 0; nf < 4; nf++) sqv[nf] = sq[b * J_ + (ch << 6) + (nf << 4) + lr];
    float mp[4], sp[4];
#pragma unroll
    for (int r = 0; r < 4; r++) {
        float m = -1e30f;
#pragma unroll
        for (int nf = 0; nf < 4; nf++) { acc[nf][r] += sqv[nf]; m = fmaxf(m, acc[nf][r]); }
#pragma unroll
        for (int msk = 8; msk >= 1; msk >>= 1) m = fmaxf(m, __shfl_xor(m, msk));
        float s = 0.f;
#pragma unroll
        for (int nf = 0; nf < 4; nf++) { float e = __expf(acc[nf][r] - m); acc[nf][r] = e; s += e; }
#pragma unroll
        for (int msk = 8; msk >= 1; msk >>= 1) s += __shfl_xor(s, msk);
        mp[r] = m; sp[r] = s;
    }
    __syncthreads();               // S5: B1 free (all waves done with mfmaA(B1,3))
    if (lr == 0) {
#pragma unroll
        for (int r = 0; r < 4; r++) {
            int row = R0 + (lq << 2) + r;
            sc[(row << 2) + (ch << 1)] = mp[r];
            sc[(row << 2) + (ch << 1) + 1] = sp[r];
        }
    }
    __syncthreads();               // S5b: sc visible

    // ---- merge halves, write P (bf16 swizzled); keep merged maxes in regs ----
    float mm[4];
#pragma unroll
    for (int r = 0; r < 4; r++) {
        int row = R0 + (lq << 2) + r;
        float m0 = sc[(row << 2)],     s0 = sc[(row << 2) + 1];
        float m1 = sc[(row << 2) + 2], s1 = sc[(row << 2) + 3];
        float m = fmaxf(m0, m1);
        float sum = s0 * __expf(m0 - m) + s1 * __expf(m1 - m);
        float scale = __expf(mp[r] - m) / sum;
#pragma unroll
        for (int nf = 0; nf < 4; nf++) {
            int cc = (ch << 6) + (nf << 4) + lr;
            int chunk = cc >> 3;
            *(unsigned short*)(Ps + row * 256 + ((chunk ^ (row & 7)) << 4) + ((lr & 7) << 1)) =
                f2bf(acc[nf][r] * scale);
        }
        mm[r] = m;
    }
    __syncthreads();               // S6: Ps visible, sc consumed -> B1 reusable
    stageQ(B1, 1);                 // stage1 flies under first PV MFMAs

    // ---- phase B: P(32x128) . qT(256x128)^T, 4 stages ----
    int prow = R0 + lr;
    s8v pf[4];
#pragma unroll
    for (int jk = 0; jk < 4; jk++)
        pf[jk] = *(const s8v*)(Ps + prow * 256 + ((((jk << 2) + lq) ^ (prow & 7)) << 4));

    f4 acc2[8];
#pragma unroll
    for (int ai = 0; ai < 8; ai++) acc2[ai] = (f4){0.f, 0.f, 0.f, 0.f};

    auto mfmaB = [&](char* rb, int s) {
#pragma unroll
        for (int df2 = 0; df2 < 2; df2++) {
            int dr = (ch << 5) + (df2 << 4) + lr;
            int ai = (s << 1) + df2;
#pragma unroll
            for (int jk = 0; jk < 4; jk++) {
                s8v bv = *(const s8v*)(rb + (dr << 8) + ((((jk << 2) + lq) ^ (dr & 7)) << 4));
                acc2[ai] = __builtin_amdgcn_mfma_f32_16x16x32_bf16(pf[jk], bv, acc2[ai], 0, 0, 0);
            }
        }
    };

    mfmaB(B0, 0);
    __syncthreads();               // S7: B0 free
    stageQ(B0, 2);
    mfmaB(B1, 1);
    __syncthreads();               // S8: B1 free, stage2 staged
    stageQ(B1, 3);
    mfmaB(B0, 2);
    __syncthreads();               // S9: stage3 staged
    mfmaB(B1, 3);
    __syncthreads();               // S10: bufs free for epilogue

    // ---- epilogue: acc2 -> LDS (swizzled) -> f4-coalesced nt-stores of q1,q2,q3 ----
    float* cq = (float*)lds;       // 32 rows x 256 cols fp32 = 32 KB
#pragma unroll
    for (int s2 = 0; s2 < 4; s2++)
#pragma unroll
        for (int df2 = 0; df2 < 2; df2++) {
            int col = (s2 << 6) + (ch << 5) + (df2 << 4) + lr;
            int ai = (s2 << 1) + df2;
            int chunk = col >> 2;
#pragma unroll
            for (int r = 0; r < 4; r++) {
                int row = R0 + (lq << 2) + r;
                *(float*)((char*)cq + (row << 10) + ((chunk ^ (row & 7)) << 4) + ((col & 3) << 2)) = acc2[ai][r];
            }
        }
    __syncthreads();               // S11

    {
        int row = tid >> 3;                   // 0..31
        int o = b * T_ + t0 + row;
        const float* crow = ctx + o * D_;
        float* orow = out + o * 1024;
#pragma unroll
        for (int i = 0; i < 8; i++) {
            int col4 = (i << 5) + ((tid & 7) << 2);
            int chunk = col4 >> 2;
            f4 val = *(const f4*)((char*)cq + (row << 10) + ((chunk ^ (row & 7)) << 4));
            f4 cx = *(const f4*)(crow + col4);
            f4 v3 = cx * val;
            __builtin_nontemporal_store(cx, (f4*)(orow + col4));
            __builtin_nontemporal_store(val, (f4*)(orow + 256 + col4));
            __builtin_nontemporal_store(v3, (f4*)(orow + 512 + col4));
        }
    }

    // ---- q2c partial: wave (rg,ch) covers rows rg*16..+15, d = ch*128 + l*2 (+0,1); ctx L2-hot ----
    {
        float m16[16];
#pragma unroll
        for (int i = 0; i < 16; i++) m16[i] = __shfl(mm[i & 3], (i >> 2) << 4);
        float mw = -1e30f;
#pragma unroll
        for (int i = 0; i < 16; i++) mw = fmaxf(mw, m16[i]);
        const float* cp = ctx + (b * T_ + t0 + R0) * D_ + (ch << 7) + (l << 1);
        f2 p = (f2){0.f, 0.f};
        float sw_ = 0.f;
#pragma unroll 4
        for (int t = 0; t < 16; t++) {
            float e = __expf(m16[t] - mw);
            sw_ += e;
            f2 cv = *(const f2*)(cp + t * D_);
            p.x += e * cv.x; p.y += e * cv.y;
        }
        int pidx = (((b << 5) | tc) << 1) | rg;
        *(f2*)(pq2c + (pidx << 8) + (ch << 7) + (l << 1)) = p;
        if (ch == 0 && l == 0) { pms[pidx * 2] = mw; pms[pidx * 2 + 1] = sw_; }
    }
}

// ---------------- K_tail: merge 64 partials -> q2c; write quarter 4 ----------------
__global__ __launch_bounds__(256) void k_tail(const float* __restrict__ ctx,
                                              const float* __restrict__ pq2c, const float* __restrict__ pms,
                                              float* __restrict__ out) {
    int b = blockIdx.x >> 5, tc = blockIdx.x & 31;
    int tid = threadIdx.x;
    const float* pm = pms + b * 128;

    float mx = -1e30f;
#pragma unroll 8
    for (int i = 0; i < 64; i++) mx = fmaxf(mx, pm[2 * i]);
    float sm = 0.f, q2 = 0.f;
#pragma unroll 4
    for (int i = 0; i < 64; i++) {
        float e = __expf(pm[2 * i] - mx);
        sm += pm[2 * i + 1] * e;
        q2 += e * pq2c[((b << 6) + i) * 256 + tid];
    }
    q2 /= sm;
    __shared__ float q2s[256];
    q2s[tid] = q2;
    __syncthreads();

    int row = tid >> 3;
    int o = b * T_ + tc * 32 + row;
    const float* crow = ctx + o * D_;
    float* orow = out + o * 1024;
#pragma unroll
    for (int i = 0; i < 8; i++) {
        int col4 = (i << 5) + ((tid & 7) << 2);
        f4 cx = *(const f4*)(crow + col4);
        f4 qv = *(const f4*)&q2s[col4];
        f4 r = cx * qv;
        __builtin_nontemporal_store(r, (f4*)(orow + 768 + col4));
    }
}

extern "C" void kernel_launch(void* const* d_in, const int* in_sizes, int n_in,
                              void* d_out, int out_size, void* d_ws, size_t ws_size,
                              hipStream_t stream) {
    const float* ctx   = (const float*)d_in[0];
    const float* query = (const float*)d_in[1];
    const float* w     = (const float*)d_in[2];
    float* out = (float*)d_out;

    unsigned short* Bqh = (unsigned short*)d_ws;        // 2 MB
    unsigned short* qTh = Bqh + B_ * J_ * D_;           // 2 MB
    float* fws = (float*)(qTh + B_ * J_ * D_);
    float* sq   = fws;                                  // 4096 floats
    float* pq2c = fws + 4096;                           // 2048*256 floats (2 MB)
    float* pms  = fws + 4096 + 2048 * 256;              // 4096 floats

    k_pre<<<B_ * 8, 256, 0, stream>>>(query, w, Bqh, sq, qTh);
    k_main<<<B_ * (T_ / 32), 256, 0, stream>>>(ctx, Bqh, qTh, sq, pq2c, pms, out);
    k_tail<<<B_ * 32, 256, 0, stream>>>(ctx, pq2c, pms, out);
}